// Round 5
// baseline (18223.872 us; speedup 1.0000x reference)
//
#include <hip/hip_runtime.h>
#include <cstdint>
#include <cstddef>

// Problem constants: B=64, T=512, D=256, H=512
#define T_STEPS 512
#define D_DIM 256
#define H_DIM 512
#define B_SZ 64

// rnn_scan8 = scan3 structure (4 col-groups x 128, grid 256 = 1 WG/CU,
// w[128] register-resident, NO inline asm) with the exchange split into
// DATA (raw 4B floats, relaxed agent stores) + FLAG (one u64 per producer
// WAVE, RELEASE agent store => per-wave vmcnt(0) drains the 64 data stores
// to the coherence point before the flag lands). Consumers: ONE lane per
// wave polls its single wave-uniform flag (2048 pollers chip-wide vs scan3's
// 128K -- the round-4 theory is that the poll storm, not intrinsic MALL
// latency, dominates the RT), then __threadfence() + one-shot relaxed agent
// gather of z. Parity/progress invariant identical to the proven scan3:
// a producer overwrites parity p at step t only after consuming step t-1,
// which implies every quartet member finished consuming step t-2 (same p).
#define NCG 4
#define CGW (H_DIM / NCG)   // 128
#define NTH 512

// d_ws layout: zdata f32[64][2][512] = 256 KB; flags u64[64][2][4][2] = 8 KB.
// Flags are tag-compared (tags 1..512); 0xAAAAAAAA poison never matches.
// zdata needs no tag/poison guard -- it is only read after its flag.

// ---------------------------------------------------------------------------
// Kernel 1: xproj = inputs @ Wx + bias  ->  d_out  [B*T, H]   (unchanged)
// ---------------------------------------------------------------------------
#define BM 64
#define BN 128
#define BK 32

__global__ __launch_bounds__(256)
void xproj_gemm(const float* __restrict__ A, const float* __restrict__ Bm,
                const float* __restrict__ bias, float* __restrict__ C,
                int M, int N, int K) {
    __shared__ float As[BK][BM];
    __shared__ float Bs[BK][BN];

    const int tid = threadIdx.x;
    const int tx = tid & 15;
    const int ty = tid >> 4;
    const int row0 = blockIdx.y * BM;
    const int col0 = blockIdx.x * BN;

    float acc[4][8];
    #pragma unroll
    for (int i = 0; i < 4; ++i)
        #pragma unroll
        for (int j = 0; j < 8; ++j) acc[i][j] = 0.0f;

    for (int kt = 0; kt < K; kt += BK) {
        #pragma unroll
        for (int i = 0; i < 2; ++i) {
            int q  = tid + i * 256;
            int m  = q >> 3;
            int k4 = (q & 7) << 2;
            float4 v = *(const float4*)&A[(size_t)(row0 + m) * K + kt + k4];
            As[k4 + 0][m] = v.x; As[k4 + 1][m] = v.y;
            As[k4 + 2][m] = v.z; As[k4 + 3][m] = v.w;
        }
        #pragma unroll
        for (int i = 0; i < 4; ++i) {
            int q  = tid + i * 256;
            int kk = q >> 5;
            int n4 = (q & 31) << 2;
            *(float4*)&Bs[kk][n4] = *(const float4*)&Bm[(size_t)(kt + kk) * N + col0 + n4];
        }
        __syncthreads();
        #pragma unroll
        for (int k = 0; k < BK; ++k) {
            float4 a  = *(const float4*)&As[k][ty << 2];
            float4 b0 = *(const float4*)&Bs[k][tx << 2];
            float4 b1 = *(const float4*)&Bs[k][(tx << 2) + 64];
            float av[4] = {a.x, a.y, a.z, a.w};
            float bv[8] = {b0.x, b0.y, b0.z, b0.w, b1.x, b1.y, b1.z, b1.w};
            #pragma unroll
            for (int i = 0; i < 4; ++i)
                #pragma unroll
                for (int j = 0; j < 8; ++j)
                    acc[i][j] = fmaf(av[i], bv[j], acc[i][j]);
        }
        __syncthreads();
    }

    float bv0[4], bv1[4];
    #pragma unroll
    for (int j = 0; j < 4; ++j) {
        bv0[j] = bias[col0 + (tx << 2) + j];
        bv1[j] = bias[col0 + (tx << 2) + 64 + j];
    }
    #pragma unroll
    for (int i = 0; i < 4; ++i) {
        int r = row0 + (ty << 2) + i;
        float4 o0 = make_float4(acc[i][0] + bv0[0], acc[i][1] + bv0[1],
                                acc[i][2] + bv0[2], acc[i][3] + bv0[3]);
        float4 o1 = make_float4(acc[i][4] + bv1[0], acc[i][5] + bv1[1],
                                acc[i][6] + bv1[2], acc[i][7] + bv1[3]);
        *(float4*)&C[(size_t)r * N + col0 + (tx << 2)]      = o0;
        *(float4*)&C[(size_t)r * N + col0 + (tx << 2) + 64] = o1;
    }
}

// ---------------------------------------------------------------------------
__device__ __forceinline__ float tanh_fast(float x) {
    float ax = fabsf(x);
    float e  = __expf(2.0f * ax);
    float t  = 1.0f - 2.0f / (e + 1.0f);
    return copysignf(t, x);
}

// ---------------------------------------------------------------------------
// Kernel 2: scan with data+flag split exchange, wave-leader flag polling.
// ---------------------------------------------------------------------------
__global__ __launch_bounds__(NTH)
void rnn_scan8(const float* __restrict__ Wh, const float* __restrict__ h0,
               const float* __restrict__ gamma, const float* __restrict__ beta,
               float* __restrict__ out,
               float* __restrict__ zdata,
               unsigned long long* __restrict__ flags) {
    const int r   = blockIdx.x & (B_SZ - 1);   // row; quartet shares r
    const int cg  = blockIdx.x >> 6;           // 0..3 column-group
    const int tid = threadIdx.x;               // 0..511
    const int c   = tid & (CGW - 1);           // 0..127
    const int kc  = tid >> 7;                  // 0..3 (wave-uniform)

    __shared__ float h_s[H_DIM];
    __shared__ float part_s[NCG][CGW];
    __shared__ float wred_s[16];

    // Wh register slice: w[j] = Wh[kc*128 + j][cg*128 + c]
    float w[128];
    #pragma unroll
    for (int j = 0; j < 128; ++j)
        w[j] = Wh[(size_t)(kc * 128 + j) * H_DIM + cg * CGW + c];

    h_s[tid] = h0[r * H_DIM + tid];
    const float g_own = gamma[tid];
    const float b_own = beta[tid];
    float* outrow = out + (size_t)r * T_STEPS * H_DIM;

    float* zd0 = zdata + (size_t)r * 2 * H_DIM;
    unsigned long long* fl0 = flags + (size_t)r * 2 * (NCG * 2);

    // consumer-side wave-uniform flag coordinates for own column `tid`
    const int fo = tid >> 7;            // owner WG (== kc)
    const int fw = (tid >> 6) & 1;      // owner producer wave

    float xp_next = 0.0f;
    if (tid < CGW)
        xp_next = __builtin_nontemporal_load(&outrow[cg * CGW + tid]);
    __syncthreads();

    for (int t = 0; t < T_STEPS; ++t) {
        float* zd = zd0 + (size_t)(t & 1) * H_DIM;
        unsigned long long* fl = fl0 + (size_t)(t & 1) * (NCG * 2);
        const unsigned long long tag = (unsigned long long)(t + 1);
        const float xp = xp_next;

        // partial z for own slice: 4 independent FMA chains (scan3 order)
        {
            const float4* h4 = (const float4*)&h_s[kc * 128];
            float a0 = 0.0f, a1 = 0.0f, a2 = 0.0f, a3 = 0.0f;
            #pragma unroll
            for (int j4 = 0; j4 < 32; ++j4) {
                float4 hv = h4[j4];
                a0 = fmaf(w[4 * j4 + 0], hv.x, a0);
                a1 = fmaf(w[4 * j4 + 1], hv.y, a1);
                a2 = fmaf(w[4 * j4 + 2], hv.z, a2);
                a3 = fmaf(w[4 * j4 + 3], hv.w, a3);
            }
            part_s[kc][c] = (a0 + a1) + (a2 + a3);
        }
        __syncthreads();                                   // barrier A

        // producers: combine (scan3 fold order), publish data then flag.
        // RELEASE on the flag waits this WAVE's vmcnt(0) -> the wave's 64
        // data stores are at the coherence point before the flag lands.
        if (tid < CGW) {
            float z = xp + part_s[0][tid] + part_s[1][tid]
                         + part_s[2][tid] + part_s[3][tid];
            __hip_atomic_store(&zd[cg * CGW + tid], z,
                               __ATOMIC_RELAXED, __HIP_MEMORY_SCOPE_AGENT);
            if ((tid & 63) == 63)
                __hip_atomic_store(&fl[cg * 2 + (tid >> 6)], tag,
                                   __ATOMIC_RELEASE, __HIP_MEMORY_SCOPE_AGENT);
        }

        // prefetch next xp while the publish drains
        if (tid < CGW && t + 1 < T_STEPS)
            xp_next = __builtin_nontemporal_load(
                &outrow[(size_t)(t + 1) * H_DIM + cg * CGW + tid]);

        // wave leader polls the single flag covering this wave's 64 columns
        if ((tid & 63) == 0) {
            while (__hip_atomic_load(&fl[fo * 2 + fw], __ATOMIC_RELAXED,
                                     __HIP_MEMORY_SCOPE_AGENT) != tag) {}
        }
        __threadfence();   // order: flag observed before the z gather below

        // one-shot gather of own column's z (relaxed agent: cache-bypassing)
        float z = __hip_atomic_load(&zd[tid], __ATOMIC_RELAXED,
                                    __HIP_MEMORY_SCOPE_AGENT);

        // LN stats over 512: identical fold to scan3
        float s = z, q = z * z;
        #pragma unroll
        for (int o = 32; o > 0; o >>= 1) {
            s += __shfl_down(s, o, 64);
            q += __shfl_down(q, o, 64);
        }
        const int wid = tid >> 6;
        if ((tid & 63) == 0) { wred_s[wid] = s; wred_s[8 + wid] = q; }
        __syncthreads();                                   // barrier B
        float S = 0.0f, Q = 0.0f;
        #pragma unroll
        for (int i = 0; i < 8; ++i) { S += wred_s[i]; Q += wred_s[8 + i]; }
        float mean = S * (1.0f / H_DIM);
        float var  = Q * (1.0f / H_DIM) - mean * mean;
        float rstd = rsqrtf(var + 1e-3f);                  // keras LN eps

        float hn = tanh_fast((z - mean) * rstd * g_own + b_own);
        if (kc == cg) outrow[t * H_DIM + tid] = hn;        // own slice store
        h_s[tid] = hn;            // all h_s reads ended before barrier A
        __syncthreads();                                   // barrier C
    }
}

// ---------------------------------------------------------------------------
extern "C" void kernel_launch(void* const* d_in, const int* in_sizes, int n_in,
                              void* d_out, int out_size, void* d_ws, size_t ws_size,
                              hipStream_t stream) {
    const float* inputs = (const float*)d_in[0];  // [B,T,D]
    const float* h0     = (const float*)d_in[1];  // [B,H]
    const float* Wx     = (const float*)d_in[2];  // [D,H]
    const float* Wh     = (const float*)d_in[3];  // [H,H]
    const float* bias   = (const float*)d_in[4];  // [H]
    const float* gamma  = (const float*)d_in[5];  // [H]
    const float* beta   = (const float*)d_in[6];  // [H]
    float* out = (float*)d_out;                   // [B,T,H]

    const int M = B_SZ * T_STEPS;                 // 32768
    dim3 g1(H_DIM / BN, M / BM);                  // (4, 512)
    xproj_gemm<<<g1, 256, 0, stream>>>(inputs, Wx, bias, out, M, H_DIM, D_DIM);

    // d_ws: zdata f32[64][2][512] (256 KB) then flags u64[64][2][8] (8 KB)
    float* zdata = (float*)d_ws;
    unsigned long long* flags =
        (unsigned long long*)(zdata + (size_t)B_SZ * 2 * H_DIM);

    rnn_scan8<<<B_SZ * NCG, NTH, 0, stream>>>(Wh, h0, gamma, beta, out,
                                              zdata, flags);
}

// Round 7
// 1730.502 us; speedup vs baseline: 10.5310x; 10.5310x over previous
//
#include <hip/hip_runtime.h>
#include <cstdint>
#include <cstddef>

// Problem constants: B=64, T=512, D=256, H=512
#define T_STEPS 512
#define D_DIM 256
#define H_DIM 512
#define B_SZ 64

// rnn_fused8 = xproj fused into the scan, on the scan6-PROVEN geometry:
//   8 col-groups x 64 cols, grid = 64 rows x 8 cg = 512 WGs of 512 threads,
//   __launch_bounds__(512,4) -> HARD 128-VGPR cap:
//     * always launchable (R6 lesson: (512,1) licenses >256 VGPR, which a
//       512-thread WG cannot launch -> suspected cause of the R6 failure)
//     * 2 WGs/CU -> all 512 WGs co-resident (exchange liveness trivially ok)
//     * worst case under the cap is w/wx remat from L2 -- R3 measured this
//       exact regime (VGPR=52, FETCH 562MB) at zero time cost.
// Per-thread data: w[64] (Wh slice) + wx[32] (Wx slice) = 96 regs.
// Exchange protocol = scan6 verbatim (combined (tag|z) u64 packet, relaxed
// AGENT scope, 2-parity buffer, simple do-while poll) + own-slice shortcut:
// kc==cg waves (wave-uniform) use the locally-combined z (bitwise-identical
// fold to the published packet) instead of a MALL round-trip. Shortcut is
// liveness-safe: publishes are unconditional, so no WG's progress depends
// on it; parity-overwrite invariant re-verified (neighbors' kc==cg_X waves
// read all 64 of X's columns before X can reach step t+2).
// Fusion deletes: the 130us GEMM dispatch, its 64MB C-write, the 64MB xp
// re-read. NO inline asm, NO fences/release (R5 lesson), simple CFG.
#define NCG 8
#define CGW (H_DIM / NCG)   // 64
#define NTH 512

// d_ws layout: zbuf u64[64 rows][2 parity][512 cols] = 512 KB.
// 0xAAAAAAAA poison never equals a tag in 1..512; ws re-poisoned per iter.

// ---------------------------------------------------------------------------
__device__ __forceinline__ float tanh_fast(float x) {
    float ax = fabsf(x);
    float e  = __expf(2.0f * ax);
    float t  = 1.0f - 2.0f / (e + 1.0f);
    return copysignf(t, x);
}

// ---------------------------------------------------------------------------
__global__ __launch_bounds__(NTH, 4)
void rnn_fused8(const float* __restrict__ Wh, const float* __restrict__ Wx,
                const float* __restrict__ inputs, const float* __restrict__ h0,
                const float* __restrict__ bias,
                const float* __restrict__ gamma, const float* __restrict__ beta,
                float* __restrict__ out,
                unsigned long long* __restrict__ zbuf) {
    const int cg  = blockIdx.x & (NCG - 1);    // 0..7 column-group
    const int r   = blockIdx.x >> 3;           // 0..63 row (octet consecutive)
    const int tid = threadIdx.x;               // 0..511
    const int c   = tid & (CGW - 1);           // 0..63
    const int kc  = tid >> 6;                  // 0..7 == wave id (uniform)

    __shared__ float h_s[H_DIM];               // 2 KB
    __shared__ float x_s[2][D_DIM];            // 2 KB double-buffered x[t]
    __shared__ float part_s[NCG][CGW];         // 2 KB
    __shared__ float wred_s[16];

    // Wh slice: w[j] = Wh[kc*64 + j][cg*64 + c]      (64 regs)
    float w[64];
    #pragma unroll
    for (int j = 0; j < 64; ++j)
        w[j] = Wh[(size_t)(kc * 64 + j) * H_DIM + cg * CGW + c];

    // Wx slice: wx[j] = Wx[kc*32 + j][cg*64 + c]     (32 regs)
    float wx[32];
    #pragma unroll
    for (int j = 0; j < 32; ++j)
        wx[j] = Wx[(size_t)(kc * 32 + j) * H_DIM + cg * CGW + c];

    h_s[tid] = h0[r * H_DIM + tid];
    const float* inrow = inputs + (size_t)r * T_STEPS * D_DIM;
    if (tid < D_DIM) x_s[0][tid] = inrow[tid];         // stage x[0]

    const float g_own = gamma[tid];
    const float b_own = beta[tid];
    const float b_pub = bias[cg * CGW + c];            // bias for own column
    float* outrow = out + (size_t)r * T_STEPS * H_DIM;
    unsigned long long* zrow0 = zbuf + (size_t)(r * 2) * H_DIM;
    __syncthreads();

    for (int t = 0; t < T_STEPS; ++t) {
        unsigned long long* zrow = zrow0 + (size_t)(t & 1) * H_DIM;
        const unsigned int tag = (unsigned int)(t + 1);

        // ---- phase 1: partial z = (Wh-slice)^T h + (Wx-slice)^T x ----
        float a0 = 0.0f, a1 = 0.0f, a2 = 0.0f, a3 = 0.0f;
        {
            const float4* h4 = (const float4*)&h_s[kc * CGW];
            #pragma unroll
            for (int j4 = 0; j4 < 16; ++j4) {
                float4 hv = h4[j4];
                a0 = fmaf(w[4 * j4 + 0], hv.x, a0);
                a1 = fmaf(w[4 * j4 + 1], hv.y, a1);
                a2 = fmaf(w[4 * j4 + 2], hv.z, a2);
                a3 = fmaf(w[4 * j4 + 3], hv.w, a3);
            }
            const float4* x4 = (const float4*)&x_s[t & 1][kc * 32];
            #pragma unroll
            for (int j4 = 0; j4 < 8; ++j4) {
                float4 xv = x4[j4];
                a0 = fmaf(wx[4 * j4 + 0], xv.x, a0);
                a1 = fmaf(wx[4 * j4 + 1], xv.y, a1);
                a2 = fmaf(wx[4 * j4 + 2], xv.z, a2);
                a3 = fmaf(wx[4 * j4 + 3], xv.w, a3);
            }
        }
        part_s[kc][c] = (a0 + a1) + (a2 + a3);
        __syncthreads();                                   // barrier A

        // ---- combine by ALL threads (deterministic fold -> same bits) ----
        float zloc = b_pub;
        #pragma unroll
        for (int k = 0; k < NCG; ++k) zloc += part_s[k][c];

        // wave 0 publishes the WG's 64 columns (scan6 protocol verbatim)
        if (tid < CGW) {
            unsigned long long pkt = ((unsigned long long)tag << 32)
                                   | (unsigned long long)__float_as_uint(zloc);
            __hip_atomic_store(&zrow[cg * CGW + tid], pkt,
                               __ATOMIC_RELAXED, __HIP_MEMORY_SCOPE_AGENT);
        }

        // issue next x[t+1] load while the publish/poll RT elapses
        const int tn = (t + 1 < T_STEPS) ? t + 1 : t;
        float xnext = 0.0f;
        if (tid < D_DIM) xnext = inrow[(size_t)tn * D_DIM + tid];

        // ---- gather z for global column `tid` ----
        float z;
        if (kc == cg) {
            z = zloc;                      // own slice: no MALL round-trip
        } else {
            unsigned long long pkt;
            do {
                pkt = __hip_atomic_load(&zrow[tid], __ATOMIC_RELAXED,
                                        __HIP_MEMORY_SCOPE_AGENT);
            } while ((unsigned int)(pkt >> 32) != tag);
            z = __uint_as_float((unsigned int)pkt);
        }

        // ---- LN stats over 512: fold identical to scan3/scan6 ----
        float s = z, q = z * z;
        #pragma unroll
        for (int o = 32; o > 0; o >>= 1) {
            s += __shfl_down(s, o, 64);
            q += __shfl_down(q, o, 64);
        }
        if ((tid & 63) == 0) { wred_s[kc] = s; wred_s[8 + kc] = q; }
        __syncthreads();                                   // barrier B
        float S = 0.0f, Q = 0.0f;
        #pragma unroll
        for (int i = 0; i < 8; ++i) { S += wred_s[i]; Q += wred_s[8 + i]; }
        float mean = S * (1.0f / H_DIM);
        float var  = Q * (1.0f / H_DIM) - mean * mean;
        float rstd = rsqrtf(var + 1e-3f);                  // keras LN eps

        float hn = tanh_fast((z - mean) * rstd * g_own + b_own);
        if (kc == cg) outrow[(size_t)t * H_DIM + tid] = hn; // own slice store
        h_s[tid] = hn;              // all h_s reads ended before barrier A
        if (tid < D_DIM) x_s[(t + 1) & 1][tid] = xnext;     // stage x[t+1]
        __syncthreads();                                   // barrier C
    }
}

// ---------------------------------------------------------------------------
extern "C" void kernel_launch(void* const* d_in, const int* in_sizes, int n_in,
                              void* d_out, int out_size, void* d_ws, size_t ws_size,
                              hipStream_t stream) {
    const float* inputs = (const float*)d_in[0];  // [B,T,D]
    const float* h0     = (const float*)d_in[1];  // [B,H]
    const float* Wx     = (const float*)d_in[2];  // [D,H]
    const float* Wh     = (const float*)d_in[3];  // [H,H]
    const float* bias   = (const float*)d_in[4];  // [H]
    const float* gamma  = (const float*)d_in[5];  // [H]
    const float* beta   = (const float*)d_in[6];  // [H]
    float* out = (float*)d_out;                   // [B,T,H]

    unsigned long long* zbuf = (unsigned long long*)d_ws;  // 512 KB

    // single fused dispatch: xproj folded into the scan
    rnn_fused8<<<B_SZ * NCG, NTH, 0, stream>>>(Wh, Wx, inputs, h0, bias,
                                               gamma, beta, out, zbuf);
}

// Round 8
// 1603.200 us; speedup vs baseline: 11.3672x; 1.0794x over previous
//
#include <hip/hip_runtime.h>
#include <cstdint>
#include <cstddef>

// Problem constants: B=64, T=512, D=256, H=512
#define T_STEPS 512
#define D_DIM 256
#define H_DIM 512
#define B_SZ 64

// rnn_fused4 = the PROVEN scan3 kernel (4 col-groups x 128 cols, grid 256 =
// 1 WG/CU, w[128] Wh-slice register-resident, combined (tag|z) u64 packet,
// relaxed AGENT scope, 2-parity buffer, simple all-thread do-while poll)
// with xproj fused via LDS-resident Wx:
//   - Wx[:, cg*128..+127] slice (256x128 fp32 = 128 KB) lives in LDS,
//     XOR-swizzled float4 layout -> balanced banks on the stride-row reads.
//     NOT in registers: R7 proved register remat of fused weights is
//     L2-BW-bound (393 KB/step/CU > per-CU L2 BW -> 3.5us steps).
//   - x[t] (1 KB) double-buffered in LDS, early-issue/late-write staging
//     (R7-proven pattern), read as wave-uniform broadcasts.
//   - __launch_bounds__(512,2): 256-VGPR cap -- launchable by construction
//     (R6 lesson) and roomy enough that w[128] stays resident (R7 lesson:
//     (512,4)'s 128 cap forced remat).
// Deletes the 129us GEMM dispatch, its 64MB C-write, the 64MB xp re-read.
// Added per-step cost: 16 swizzled b128 wx reads + 16 x broadcasts + 64 FMA.
// NO inline asm, NO fences/release (R5), simple poll CFG (R1/R4 spill rule).
#define NCG 4
#define CGW (H_DIM / NCG)   // 128
#define NTH 512

// d_ws layout: zbuf u64[64 rows][2 parity][512 cols] = 512 KB.
// 0xAAAAAAAA poison never equals a tag in 1..512; ws re-poisoned per iter.

// ---------------------------------------------------------------------------
__device__ __forceinline__ float tanh_fast(float x) {
    float ax = fabsf(x);
    float e  = __expf(2.0f * ax);
    float t  = 1.0f - 2.0f / (e + 1.0f);
    return copysignf(t, x);
}

// ---------------------------------------------------------------------------
__global__ __launch_bounds__(NTH, 2)
void rnn_fused4(const float* __restrict__ Wh, const float* __restrict__ Wx,
                const float* __restrict__ inputs, const float* __restrict__ h0,
                const float* __restrict__ bias,
                const float* __restrict__ gamma, const float* __restrict__ beta,
                float* __restrict__ out,
                unsigned long long* __restrict__ zbuf) {
    const int r   = blockIdx.x & (B_SZ - 1);   // row; quartet shares r
    const int cg  = blockIdx.x >> 6;           // 0..3 column-group
    const int tid = threadIdx.x;               // 0..511
    const int c   = tid & (CGW - 1);           // 0..127
    const int kc  = tid >> 7;                  // 0..3 (wave-uniform)

    // LDS: 128KB Wx slice + 2KB h + 2KB x(dbuf) + 2KB partials + wred
    __shared__ float4 wx4_s[CGW][D_DIM / 4];   // [c][j4], XOR-swizzled j4
    __shared__ float  h_s[H_DIM];
    __shared__ float  x_s[2][D_DIM];
    __shared__ float  part_s[NCG][CGW];
    __shared__ float  wred_s[16];

    // Wh register slice (exactly scan3): w[j] = Wh[kc*128 + j][cg*128 + c]
    float w[128];
    #pragma unroll
    for (int j = 0; j < 128; ++j)
        w[j] = Wh[(size_t)(kc * 128 + j) * H_DIM + cg * CGW + c];

    // Stage the Wx slice into LDS (one-time, coalesced reads).
    // Element (j, c2) -> wx4_s[c2][(j>>2) ^ (c2&7)][j&3]
    for (int i = 0; i < 64; ++i) {
        int flat = i * NTH + tid;              // 0..32767
        int j    = flat >> 7;                  // 0..255
        int c2   = flat & 127;
        float v  = Wx[(size_t)j * H_DIM + cg * CGW + c2];
        ((float*)&wx4_s[c2][(j >> 2) ^ (c2 & 7)])[j & 3] = v;
    }

    h_s[tid] = h0[r * H_DIM + tid];
    const float* inrow = inputs + (size_t)r * T_STEPS * D_DIM;
    if (tid < D_DIM) x_s[0][tid] = inrow[tid];           // stage x[0]

    const float g_own = gamma[tid];
    const float b_own = beta[tid];
    const float b_pub = bias[cg * CGW + c];
    float* outrow = out + (size_t)r * T_STEPS * H_DIM;
    unsigned long long* zrow0 = zbuf + (size_t)(r * 2) * H_DIM;
    const int cx7 = c & 7;
    __syncthreads();

    for (int t = 0; t < T_STEPS; ++t) {
        unsigned long long* zrow = zrow0 + (size_t)(t & 1) * H_DIM;
        const unsigned int tag = (unsigned int)(t + 1);

        // ---- phase 1: partial z = (Wh-slice)^T h + (Wx-slice)^T x ----
        // 4 independent FMA chains; h/x reads are wave-uniform broadcasts,
        // wx reads are swizzle-balanced across banks.
        float a0 = 0.0f, a1 = 0.0f, a2 = 0.0f, a3 = 0.0f;
        {
            const float4* h4 = (const float4*)&h_s[kc * 128];
            #pragma unroll
            for (int j4 = 0; j4 < 32; ++j4) {
                float4 hv = h4[j4];
                a0 = fmaf(w[4 * j4 + 0], hv.x, a0);
                a1 = fmaf(w[4 * j4 + 1], hv.y, a1);
                a2 = fmaf(w[4 * j4 + 2], hv.z, a2);
                a3 = fmaf(w[4 * j4 + 3], hv.w, a3);
            }
            const float4* xrow = (const float4*)&x_s[t & 1][kc * 64];
            #pragma unroll
            for (int i = 0; i < 16; ++i) {
                float4 wv = wx4_s[c][(kc * 16 + i) ^ cx7];
                float4 xv = xrow[i];
                a0 = fmaf(wv.x, xv.x, a0);
                a1 = fmaf(wv.y, xv.y, a1);
                a2 = fmaf(wv.z, xv.z, a2);
                a3 = fmaf(wv.w, xv.w, a3);
            }
        }
        part_s[kc][c] = (a0 + a1) + (a2 + a3);
        __syncthreads();                                   // barrier A

        // producers: combine + publish (scan3 protocol, verbatim)
        if (tid < CGW) {
            float z = b_pub + part_s[0][tid] + part_s[1][tid]
                            + part_s[2][tid] + part_s[3][tid];
            unsigned long long pkt = ((unsigned long long)tag << 32)
                                   | (unsigned long long)__float_as_uint(z);
            __hip_atomic_store(&zrow[cg * CGW + tid], pkt,
                               __ATOMIC_RELAXED, __HIP_MEMORY_SCOPE_AGENT);
        }

        // issue next x[t+1] load while the publish/poll RT elapses
        const int tn = (t + 1 < T_STEPS) ? t + 1 : t;
        float xnext = 0.0f;
        if (tid < D_DIM) xnext = inrow[(size_t)tn * D_DIM + tid];

        // every thread polls the packet for global column `tid`
        unsigned long long pkt;
        do {
            pkt = __hip_atomic_load(&zrow[tid], __ATOMIC_RELAXED,
                                    __HIP_MEMORY_SCOPE_AGENT);
        } while ((unsigned int)(pkt >> 32) != tag);
        float z = __uint_as_float((unsigned int)pkt);

        // ---- LN stats over 512: fold identical to scan3 ----
        float s = z, q = z * z;
        #pragma unroll
        for (int o = 32; o > 0; o >>= 1) {
            s += __shfl_down(s, o, 64);
            q += __shfl_down(q, o, 64);
        }
        const int wid = tid >> 6;
        if ((tid & 63) == 0) { wred_s[wid] = s; wred_s[8 + wid] = q; }
        __syncthreads();                                   // barrier B
        float S = 0.0f, Q = 0.0f;
        #pragma unroll
        for (int i = 0; i < 8; ++i) { S += wred_s[i]; Q += wred_s[8 + i]; }
        float mean = S * (1.0f / H_DIM);
        float var  = Q * (1.0f / H_DIM) - mean * mean;
        float rstd = rsqrtf(var + 1e-3f);                  // keras LN eps

        float hn = tanh_fast((z - mean) * rstd * g_own + b_own);
        if (kc == cg) outrow[(size_t)t * H_DIM + tid] = hn; // own slice store
        h_s[tid] = hn;              // all h_s reads ended before barrier A
        if (tid < D_DIM) x_s[(t + 1) & 1][tid] = xnext;     // stage x[t+1]
        __syncthreads();                                   // barrier C
    }
}

// ---------------------------------------------------------------------------
extern "C" void kernel_launch(void* const* d_in, const int* in_sizes, int n_in,
                              void* d_out, int out_size, void* d_ws, size_t ws_size,
                              hipStream_t stream) {
    const float* inputs = (const float*)d_in[0];  // [B,T,D]
    const float* h0     = (const float*)d_in[1];  // [B,H]
    const float* Wx     = (const float*)d_in[2];  // [D,H]
    const float* Wh     = (const float*)d_in[3];  // [H,H]
    const float* bias   = (const float*)d_in[4];  // [H]
    const float* gamma  = (const float*)d_in[5];  // [H]
    const float* beta   = (const float*)d_in[6];  // [H]
    float* out = (float*)d_out;                   // [B,T,H]

    unsigned long long* zbuf = (unsigned long long*)d_ws;  // 512 KB

    // single fused dispatch: xproj folded into the scan (Wx slice in LDS)
    rnn_fused4<<<B_SZ * NCG, NTH, 0, stream>>>(Wh, Wx, inputs, h0, bias,
                                               gamma, beta, out, zbuf);
}

// Round 9
// 1244.957 us; speedup vs baseline: 14.6382x; 1.2878x over previous
//
#include <hip/hip_runtime.h>
#include <cstdint>
#include <cstddef>

// Problem constants: B=64, T=512, D=256, H=512
#define T_STEPS 512
#define D_DIM 256
#define H_DIM 512
#define B_SZ 64

// Scan decomposition: 4 column-groups of 128 cols per batch row.
// grid = 64 rows x 4 cg = 256 WGs of 512 threads; Wh slice (512x128 fp32 =
// 256 KB) lives entirely in registers (128 VGPR/thread), loaded once.
// Cross-WG exchange: single-hop (tag,z) 8-byte packets at AGENT scope.
//
// SESSION VERDICT (rounds 0-8): this is the verified optimum. The per-step
// serial chain is ~500cy compute + ~700cy LN/barriers + ~3500-4000cy
// agent-scope publish->poll round trip; the RT is protocol- and placement-
// irreducible at HIP level on gfx950:
//   - same-XCD vs cross-XCD quartets: identical step time (R0 vs R3)
//   - plain-store + sc0-poll L2 fast path: never engages (R1, R4)
//   - release/acquire + threadfence: compile to cache-maintenance ops,
//     18ms catastrophe (R5)
//   - fewer pollers (flag-split), more WGs/CU, in-WG row-multiplexing,
//     GEMM fusion (regs or LDS): all neutral-to-worse (R2,R3,R5,R7,R8)
//   - allocator keeps w[128] resident ONLY for this exact body shape;
//     any materially larger loop body evicts it (R1,R4,R5,R7,R8)
#define NCG 4
#define CGW (H_DIM / NCG)   // 128
#define NTH 512

// d_ws layout: zbuf : uint64 [64 rows][2 parity][512 cols]  = 512 KB
// No memset needed: 0xAAAAAAAA poison never equals a tag in 1..512.

// ---------------------------------------------------------------------------
// Kernel 1: xproj = inputs @ Wx + bias  ->  d_out  [B*T, H]
// ---------------------------------------------------------------------------
#define BM 64
#define BN 128
#define BK 32

__global__ __launch_bounds__(256)
void xproj_gemm(const float* __restrict__ A, const float* __restrict__ Bm,
                const float* __restrict__ bias, float* __restrict__ C,
                int M, int N, int K) {
    __shared__ float As[BK][BM];
    __shared__ float Bs[BK][BN];

    const int tid = threadIdx.x;
    const int tx = tid & 15;
    const int ty = tid >> 4;
    const int row0 = blockIdx.y * BM;
    const int col0 = blockIdx.x * BN;

    float acc[4][8];
    #pragma unroll
    for (int i = 0; i < 4; ++i)
        #pragma unroll
        for (int j = 0; j < 8; ++j) acc[i][j] = 0.0f;

    for (int kt = 0; kt < K; kt += BK) {
        #pragma unroll
        for (int i = 0; i < 2; ++i) {
            int q  = tid + i * 256;
            int m  = q >> 3;
            int k4 = (q & 7) << 2;
            float4 v = *(const float4*)&A[(size_t)(row0 + m) * K + kt + k4];
            As[k4 + 0][m] = v.x; As[k4 + 1][m] = v.y;
            As[k4 + 2][m] = v.z; As[k4 + 3][m] = v.w;
        }
        #pragma unroll
        for (int i = 0; i < 4; ++i) {
            int q  = tid + i * 256;
            int kk = q >> 5;
            int n4 = (q & 31) << 2;
            *(float4*)&Bs[kk][n4] = *(const float4*)&Bm[(size_t)(kt + kk) * N + col0 + n4];
        }
        __syncthreads();
        #pragma unroll
        for (int k = 0; k < BK; ++k) {
            float4 a  = *(const float4*)&As[k][ty << 2];
            float4 b0 = *(const float4*)&Bs[k][tx << 2];
            float4 b1 = *(const float4*)&Bs[k][(tx << 2) + 64];
            float av[4] = {a.x, a.y, a.z, a.w};
            float bv[8] = {b0.x, b0.y, b0.z, b0.w, b1.x, b1.y, b1.z, b1.w};
            #pragma unroll
            for (int i = 0; i < 4; ++i)
                #pragma unroll
                for (int j = 0; j < 8; ++j)
                    acc[i][j] = fmaf(av[i], bv[j], acc[i][j]);
        }
        __syncthreads();
    }

    float bv0[4], bv1[4];
    #pragma unroll
    for (int j = 0; j < 4; ++j) {
        bv0[j] = bias[col0 + (tx << 2) + j];
        bv1[j] = bias[col0 + (tx << 2) + 64 + j];
    }
    #pragma unroll
    for (int i = 0; i < 4; ++i) {
        int r = row0 + (ty << 2) + i;
        float4 o0 = make_float4(acc[i][0] + bv0[0], acc[i][1] + bv0[1],
                                acc[i][2] + bv0[2], acc[i][3] + bv0[3]);
        float4 o1 = make_float4(acc[i][4] + bv1[0], acc[i][5] + bv1[1],
                                acc[i][6] + bv1[2], acc[i][7] + bv1[3]);
        *(float4*)&C[(size_t)r * N + col0 + (tx << 2)]      = o0;
        *(float4*)&C[(size_t)r * N + col0 + (tx << 2) + 64] = o1;
    }
}

// ---------------------------------------------------------------------------
// Kernel 2: the scan. 256 WGs = 64 rows x 4 col-groups. Single-hop exchange:
// producers publish (tag|z) packets; every thread polls the packet for the
// column it needs. Thread tid handles GEMM k-chunk kc=tid>>7 for column
// c=tid&127 of its own slice, and polls/owns global column `tid` for LN/h.
// ---------------------------------------------------------------------------
__device__ __forceinline__ float tanh_fast(float x) {
    float ax = fabsf(x);
    float e  = __expf(2.0f * ax);
    float t  = 1.0f - 2.0f / (e + 1.0f);
    return copysignf(t, x);
}

__global__ __launch_bounds__(NTH)
void rnn_scan3(const float* __restrict__ Wh, const float* __restrict__ h0,
               const float* __restrict__ gamma, const float* __restrict__ beta,
               float* __restrict__ out,
               unsigned long long* __restrict__ zbuf) {
    const int r   = blockIdx.x & (B_SZ - 1);   // row; quartet shares r
    const int cg  = blockIdx.x >> 6;           // 0..3 (stride 64 -> same XCD)
    const int tid = threadIdx.x;               // 0..511
    const int c   = tid & (CGW - 1);           // 0..127
    const int kc  = tid >> 7;                  // 0..3 (wave-uniform)

    __shared__ float h_s[H_DIM];
    __shared__ float part_s[NCG][CGW];
    __shared__ float wred_s[16];

    // Wh register slice: w[j] = Wh[kc*128 + j][cg*128 + c]
    float w[128];
    #pragma unroll
    for (int j = 0; j < 128; ++j)
        w[j] = Wh[(size_t)(kc * 128 + j) * H_DIM + cg * CGW + c];

    h_s[tid] = h0[r * H_DIM + tid];            // NTH == H_DIM
    const float g_own = gamma[tid];
    const float b_own = beta[tid];
    float* outrow = out + (size_t)r * T_STEPS * H_DIM;
    unsigned long long* zrow0 = zbuf + (size_t)(r * 2) * H_DIM;
    __syncthreads();

    for (int t = 0; t < T_STEPS; ++t) {
        unsigned long long* zrow = zrow0 + (size_t)(t & 1) * H_DIM;
        const unsigned int tag = (unsigned int)(t + 1);

        // xp for producer threads (covers own slice), overlaps the GEMM
        float xp = 0.0f;
        if (tid < CGW) xp = outrow[t * H_DIM + cg * CGW + tid];

        // partial z for own slice: acc = sum_j w[j] * h[kc*128 + j]
        float acc = 0.0f;
        const float4* h4 = (const float4*)&h_s[kc * 128];
        #pragma unroll
        for (int j4 = 0; j4 < 32; ++j4) {
            float4 hv = h4[j4];
            acc = fmaf(w[4 * j4 + 0], hv.x, acc);
            acc = fmaf(w[4 * j4 + 1], hv.y, acc);
            acc = fmaf(w[4 * j4 + 2], hv.z, acc);
            acc = fmaf(w[4 * j4 + 3], hv.w, acc);
        }
        part_s[kc][c] = acc;
        __syncthreads();                                   // barrier A

        // producers: combine partials, publish (tag|z) packet — single hop
        if (tid < CGW) {
            float z = xp + part_s[0][tid] + part_s[1][tid]
                         + part_s[2][tid] + part_s[3][tid];
            unsigned long long pkt =
                ((unsigned long long)tag << 32) | (unsigned long long)__float_as_uint(z);
            __hip_atomic_store(&zrow[cg * CGW + tid], pkt,
                               __ATOMIC_RELAXED, __HIP_MEMORY_SCOPE_AGENT);
        }

        // every thread polls the packet for the column it needs
        unsigned long long pkt;
        do {
            pkt = __hip_atomic_load(&zrow[tid], __ATOMIC_RELAXED,
                                    __HIP_MEMORY_SCOPE_AGENT);
        } while ((unsigned int)(pkt >> 32) != tag);
        float z = __uint_as_float((unsigned int)pkt);

        // LN stats over 512: wave shuffle + LDS, combined redundantly by all
        float s = z, q = z * z;
        #pragma unroll
        for (int o = 32; o > 0; o >>= 1) {
            s += __shfl_down(s, o, 64);
            q += __shfl_down(q, o, 64);
        }
        const int wid = tid >> 6;
        if ((tid & 63) == 0) { wred_s[wid] = s; wred_s[8 + wid] = q; }
        __syncthreads();                                   // barrier B
        float S = 0.0f, Q = 0.0f;
        #pragma unroll
        for (int i = 0; i < 8; ++i) { S += wred_s[i]; Q += wred_s[8 + i]; }
        float mean = S * (1.0f / H_DIM);
        float var  = Q * (1.0f / H_DIM) - mean * mean;
        float rstd = rsqrtf(var + 1e-3f);                  // keras LN eps

        float hn = tanh_fast((z - mean) * rstd * g_own + b_own);
        if (kc == cg) outrow[t * H_DIM + tid] = hn;        // own slice store
        h_s[tid] = hn;            // safe: all h_s reads ended before barrier A
        __syncthreads();                                   // barrier C
    }
}

// ---------------------------------------------------------------------------
extern "C" void kernel_launch(void* const* d_in, const int* in_sizes, int n_in,
                              void* d_out, int out_size, void* d_ws, size_t ws_size,
                              hipStream_t stream) {
    const float* inputs = (const float*)d_in[0];  // [B,T,D]
    const float* h0     = (const float*)d_in[1];  // [B,H]
    const float* Wx     = (const float*)d_in[2];  // [D,H]
    const float* Wh     = (const float*)d_in[3];  // [H,H]
    const float* bias   = (const float*)d_in[4];  // [H]
    const float* gamma  = (const float*)d_in[5];  // [H]
    const float* beta   = (const float*)d_in[6];  // [H]
    float* out = (float*)d_out;                   // [B,T,H]

    unsigned long long* zbuf = (unsigned long long*)d_ws;  // 512 KB

    const int M = B_SZ * T_STEPS;                 // 32768
    dim3 g1(H_DIM / BN, M / BM);                  // (4, 512)
    xproj_gemm<<<g1, 256, 0, stream>>>(inputs, Wx, bias, out, M, H_DIM, D_DIM);

    rnn_scan3<<<B_SZ * NCG, NTH, 0, stream>>>(Wh, h0, gamma, beta, out, zbuf);
}